// Round 9
// baseline (376.983 us; speedup 1.0000x reference)
//
#include <hip/hip_runtime.h>
#include <cstdint>
#include <cstddef>

#define N_NODES   50000
#define N_EDGES   600000
#define DIM       128
#define NLAYERS   4
#define N_GRAPHS  64
#define N_PATIENTS 50
#define ROWS      32

typedef __attribute__((ext_vector_type(8))) __bf16        bf16x8;
typedef __attribute__((ext_vector_type(4))) float         f32x4;
typedef __attribute__((ext_vector_type(4))) unsigned int  u32x4;
typedef __attribute__((ext_vector_type(8))) unsigned short u16x8;

__device__ inline unsigned short f2bf(float f) {
    unsigned u = __builtin_bit_cast(unsigned, f);
    u += 0x7FFFu + ((u >> 16) & 1u);   // round-to-nearest-even
    return (unsigned short)(u >> 16);
}

__device__ inline float bf2f(unsigned short s) {
    return __builtin_bit_cast(float, (unsigned)s << 16);
}

__device__ inline f32x4 lo4(u16x8 u) {
    f32x4 r;
    r[0] = bf2f(u[0]); r[1] = bf2f(u[1]); r[2] = bf2f(u[2]); r[3] = bf2f(u[3]);
    return r;
}
__device__ inline f32x4 hi4(u16x8 u) {
    f32x4 r;
    r[0] = bf2f(u[4]); r[1] = bf2f(u[5]); r[2] = bf2f(u[6]); r[3] = bf2f(u[7]);
    return r;
}

// ---------------- CSR build ----------------

__global__ void k_count(const int* __restrict__ ei, int* __restrict__ counts) {
    int e = blockIdx.x * 256 + threadIdx.x;
    if (e < N_EDGES) atomicAdd(&counts[ei[N_EDGES + e]], 1);
}

__global__ void k_scan_a(const int* __restrict__ counts, int* __restrict__ incl,
                         int* __restrict__ bsums, int n) {
    __shared__ int s[256];
    int i = blockIdx.x * 256 + threadIdx.x;
    int v = (i < n) ? counts[i] : 0;
    s[threadIdx.x] = v;
    __syncthreads();
    for (int off = 1; off < 256; off <<= 1) {
        int t = (threadIdx.x >= off) ? s[threadIdx.x - off] : 0;
        __syncthreads();
        s[threadIdx.x] += t;
        __syncthreads();
    }
    if (i < n) incl[i] = s[threadIdx.x];
    if (threadIdx.x == 255) bsums[blockIdx.x] = s[255];
}

__global__ void k_scan_b(int* __restrict__ bsums, int nb) {
    __shared__ int s[256];
    int t = threadIdx.x;
    int v = (t < nb) ? bsums[t] : 0;
    s[t] = v;
    __syncthreads();
    for (int off = 1; off < 256; off <<= 1) {
        int u = (t >= off) ? s[t - off] : 0;
        __syncthreads();
        s[t] += u;
        __syncthreads();
    }
    if (t < nb) bsums[t] = s[t];
}

__global__ void k_scan_c(const int* __restrict__ counts, const int* __restrict__ incl,
                         const int* __restrict__ bsums, int* __restrict__ row_ptr,
                         int* __restrict__ cursor, int n) {
    int i = blockIdx.x * 256 + threadIdx.x;
    if (i < n) {
        int off = blockIdx.x ? bsums[blockIdx.x - 1] : 0;
        int ex  = incl[i] - counts[i] + off;
        row_ptr[i] = ex;
        cursor[i]  = ex;
        if (i == n - 1) row_ptr[n] = incl[i] + off;
    }
}

__global__ void k_fill(const int* __restrict__ ei, int* __restrict__ cursor,
                       int* __restrict__ esorted) {
    int e = blockIdx.x * 256 + threadIdx.x;
    if (e < N_EDGES) {
        int d   = ei[N_EDGES + e];
        int pos = atomicAdd(&cursor[d], 1);
        esorted[pos] = ei[e];
    }
}

// ---------------- x -> bf16 copy (layer 0 gather input) ----------------

__global__ void k_prep(const float* __restrict__ x, unsigned short* __restrict__ xb) {
    int idx = blockIdx.x * 256 + threadIdx.x;        // one u16x8 per thread
    if (idx < N_NODES * DIM / 8) {
        f32x4 v0 = *(const f32x4*)(x + (size_t)idx * 8);
        f32x4 v1 = *(const f32x4*)(x + (size_t)idx * 8 + 4);
        u16x8 o = { f2bf(v0[0]), f2bf(v0[1]), f2bf(v0[2]), f2bf(v0[3]),
                    f2bf(v1[0]), f2bf(v1[1]), f2bf(v1[2]), f2bf(v1[3]) };
        *(u16x8*)(xb + (size_t)idx * 8) = o;
    }
}

// ---------------- W precombine: Wt[l][c][k] = bf16(Wcat[k][c]) ----------------

__global__ void k_wt(const float* __restrict__ Wroot, const float* __restrict__ Wrel,
                     unsigned short* __restrict__ Wt) {
    int idx = blockIdx.x * 256 + threadIdx.x;   // l*32768 + c*256 + k
    if (idx < NLAYERS * DIM * 256) {
        int l = idx >> 15;
        int c = (idx >> 8) & 127;
        int k = idx & 255;
        float v = (k < 128) ? Wroot[l * 16384 + k * 128 + c]
                            : Wrel[l * 16384 + (k - 128) * 128 + c];
        Wt[idx] = f2bf(v);
    }
}

// ---------------- gather-only: agg[row] = sum of neighbor rows (bf16) ----------------

__global__ __launch_bounds__(256) void k_agg(
    const unsigned short* __restrict__ xb,
    unsigned short* __restrict__ aggb,
    const int* __restrict__ row_ptr, const int* __restrict__ esrc)
{
    int tid = threadIdx.x;
    int grp = tid >> 4, li = tid & 15;        // 16 groups x 16 lanes; one row per group
    int grow = blockIdx.x * 16 + grp;
    if (grow >= N_NODES) return;
    int beg = row_ptr[grow], end = row_ptr[grow + 1];
    f32x4 a0 = 0.f, a1 = 0.f, b0 = 0.f, b1 = 0.f;
    int e = beg;
    for (; e + 5 < end; e += 6) {
        int s0 = esrc[e],     s1 = esrc[e + 1], s2 = esrc[e + 2];
        int s3 = esrc[e + 3], s4 = esrc[e + 4], s5 = esrc[e + 5];
        u16x8 u0 = *(const u16x8*)(xb + (size_t)s0 * DIM + li * 8);
        u16x8 u1 = *(const u16x8*)(xb + (size_t)s1 * DIM + li * 8);
        u16x8 u2 = *(const u16x8*)(xb + (size_t)s2 * DIM + li * 8);
        u16x8 u3 = *(const u16x8*)(xb + (size_t)s3 * DIM + li * 8);
        u16x8 u4 = *(const u16x8*)(xb + (size_t)s4 * DIM + li * 8);
        u16x8 u5 = *(const u16x8*)(xb + (size_t)s5 * DIM + li * 8);
        a0 += lo4(u0); a1 += hi4(u0);
        b0 += lo4(u1); b1 += hi4(u1);
        a0 += lo4(u2); a1 += hi4(u2);
        b0 += lo4(u3); b1 += hi4(u3);
        a0 += lo4(u4); a1 += hi4(u4);
        b0 += lo4(u5); b1 += hi4(u5);
    }
    for (; e < end; ++e) {
        int s0 = esrc[e];
        u16x8 u0 = *(const u16x8*)(xb + (size_t)s0 * DIM + li * 8);
        a0 += lo4(u0); a1 += hi4(u0);
    }
    a0 += b0; a1 += b1;
    u16x8 o = { f2bf(a0[0]), f2bf(a0[1]), f2bf(a0[2]), f2bf(a0[3]),
                f2bf(a1[0]), f2bf(a1[1]), f2bf(a1[2]), f2bf(a1[3]) };
    *(u16x8*)(aggb + (size_t)grow * DIM + li * 8) = o;
}

// ---------------- GEMM + LN + ELU + residual (512 threads, 32 rows) ----------------

__global__ __launch_bounds__(512, 4) void k_gemm(
    const float* __restrict__ xin,                // f32 x (residual + GEMM A source)
    const unsigned short* __restrict__ aggb,      // bf16 agg
    float* __restrict__ xout,                     // f32 x out
    unsigned short* __restrict__ xbnext,          // bf16 mirror out (may be null)
    const unsigned short* __restrict__ Wt,        // [128][256] bf16, linear
    const float* __restrict__ bconv, const float* __restrict__ gamma,
    const float* __restrict__ beta,
    const float* __restrict__ bW, const float* __restrict__ bb,
    float* __restrict__ boundary, int last)
{
    __shared__ __align__(16) unsigned short x2s[ROWS * 256];   // 16 KB, XOR-swizzled
    __shared__ float rsum[ROWS][4], rsq[ROWS][4], rbl[ROWS][4];
    const int tid     = threadIdx.x;
    const int rowbase = blockIdx.x * ROWS;
    const int lane = tid & 63, w = tid >> 6;

    // epilogue ids (needed now for residual prefetch)
    int colb = lane & 15, kg = lane >> 4;
    int rt = w >> 2, cq = w & 3;

    // PREFETCH residual values early (T14): latency hides under staging + MFMA
    float xpre[4][2];
    #pragma unroll
    for (int j = 0; j < 4; j++) {
        int grow = rowbase + rt * 16 + kg * 4 + j;
        #pragma unroll
        for (int cb = 0; cb < 2; cb++) {
            int col = cq * 32 + cb * 16 + colb;
            xpre[j][cb] = (grow < N_NODES) ? xin[(size_t)grow * DIM + col] : 0.f;
        }
    }

    // stage: f2bf(xin row) -> LDS cols [0,128), agg row -> cols [128,256)
    {
        int grp = tid >> 4, li = tid & 15;
        int grow = rowbase + grp;
        int rx = (grp & 7) << 4;
        u16x8 v = { 0, 0, 0, 0, 0, 0, 0, 0 };
        u16x8 a = { 0, 0, 0, 0, 0, 0, 0, 0 };
        if (grow < N_NODES) {
            f32x4 v0 = *(const f32x4*)(xin + (size_t)grow * DIM + li * 8);
            f32x4 v1 = *(const f32x4*)(xin + (size_t)grow * DIM + li * 8 + 4);
            v = u16x8{ f2bf(v0[0]), f2bf(v0[1]), f2bf(v0[2]), f2bf(v0[3]),
                       f2bf(v1[0]), f2bf(v1[1]), f2bf(v1[2]), f2bf(v1[3]) };
            a = *(const u16x8*)(aggb + (size_t)grow * DIM + li * 8);
        }
        *(u16x8*)((char*)x2s + ((grp * 512 + li * 16) ^ rx)) = v;
        *(u16x8*)((char*)x2s + ((grp * 512 + 256 + li * 16) ^ rx)) = a;
    }
    __syncthreads();

    // GEMM: [32x256] @ [256x128]. Wave w: rowtile rt, colquarter cq.
    u32x4 araw[8];
    {
        int row  = rt * 16 + colb;
        int base = row * 512 + kg * 16;
        int rx   = (row & 7) << 4;
        #pragma unroll
        for (int ks = 0; ks < 8; ks++) {
            int byteoff = (base + ks * 64) ^ rx;
            araw[ks] = *(const u32x4*)((const char*)x2s + byteoff);
        }
    }

    f32x4 acc[2];
    acc[0] = 0.0f; acc[1] = 0.0f;

    #pragma unroll
    for (int cb = 0; cb < 2; cb++) {
        const unsigned short* wp = Wt + ((cq * 32 + cb * 16 + colb) * 256 + kg * 8);
        #pragma unroll
        for (int ks = 0; ks < 8; ks++) {
            u32x4 braw = *(const u32x4*)(wp + ks * 32);
            acc[cb] = __builtin_amdgcn_mfma_f32_16x16x32_bf16(
                __builtin_bit_cast(bf16x8, araw[ks]),
                __builtin_bit_cast(bf16x8, braw), acc[cb], 0, 0, 0);
        }
    }

    // epilogue part 1: per-row partial sums (32 cols per wave) -> LDS slots
    float hv[4][2];
    #pragma unroll
    for (int j = 0; j < 4; j++) {
        float ps = 0.f, pq = 0.f;
        #pragma unroll
        for (int cb = 0; cb < 2; cb++) {
            int col = cq * 32 + cb * 16 + colb;
            float h = acc[cb][j] + bconv[col];
            hv[j][cb] = h; ps += h; pq += h * h;
        }
        #pragma unroll
        for (int m = 1; m < 16; m <<= 1) {
            ps += __shfl_xor(ps, m);
            pq += __shfl_xor(pq, m);
        }
        if (colb == 0) {
            int lr = rt * 16 + kg * 4 + j;
            rsum[lr][cq] = ps;
            rsq[lr][cq]  = pq;
        }
    }
    __syncthreads();

    // epilogue part 2: LN, ELU, residual from prefetched regs, f32+bf16 store
    #pragma unroll
    for (int j = 0; j < 4; j++) {
        int lr   = rt * 16 + kg * 4 + j;
        int grow = rowbase + lr;
        float sum = rsum[lr][0] + rsum[lr][1] + rsum[lr][2] + rsum[lr][3];
        float sq  = rsq[lr][0] + rsq[lr][1] + rsq[lr][2] + rsq[lr][3];
        float mean = sum * (1.f / 128.f);
        float var  = sq * (1.f / 128.f) - mean * mean;
        float rs   = rsqrtf(var + 1e-5f);
        float bl = 0.f;
        if (grow < N_NODES) {
            #pragma unroll
            for (int cb = 0; cb < 2; cb++) {
                int col  = cq * 32 + cb * 16 + colb;
                float hn = (hv[j][cb] - mean) * rs * gamma[col] + beta[col];
                hn = hn > 0.f ? hn : (expf(hn) - 1.f);
                float xo = hn + xpre[j][cb];
                xout[(size_t)grow * DIM + col] = xo;
                if (xbnext) xbnext[(size_t)grow * DIM + col] = f2bf(xo);
                bl += xo * bW[col];
            }
        }
        if (last) {
            #pragma unroll
            for (int m = 1; m < 16; m <<= 1) bl += __shfl_xor(bl, m);
            if (colb == 0) rbl[lr][cq] = bl;
        }
    }
    if (last) {
        __syncthreads();
        if (tid < ROWS && rowbase + tid < N_NODES)
            boundary[rowbase + tid] = rbl[tid][0] + rbl[tid][1] + rbl[tid][2] + rbl[tid][3] + bb[0];
    }
}

// ---------------- mean-pool per graph (batch is sorted, x f32) ----------------

__global__ void k_pool(const float* __restrict__ x, const int* __restrict__ batch,
                       float* __restrict__ pooled, int* __restrict__ gcount) {
    __shared__ float s[128];
    int g = blockIdx.x >> 4, q = blockIdx.x & 15;
    int lo = 0, hi = N_NODES;
    while (lo < hi) { int m = (lo + hi) >> 1; if (batch[m] < g) lo = m + 1; else hi = m; }
    int s0 = lo;
    lo = 0; hi = N_NODES;
    while (lo < hi) { int m = (lo + hi) >> 1; if (batch[m] < g + 1) lo = m + 1; else hi = m; }
    int e0  = lo;
    int len = e0 - s0;
    int r0 = s0 + (int)((long long)len * q / 16);
    int r1 = s0 + (int)((long long)len * (q + 1) / 16);
    int col = threadIdx.x & 127, half = threadIdx.x >> 7;
    float acc = 0.f;
    for (int r = r0 + half; r < r1; r += 2) acc += x[(size_t)r * DIM + col];
    if (half) s[col] = acc;
    __syncthreads();
    if (!half) {
        acc += s[col];
        atomicAdd(&pooled[g * DIM + col], acc);
    }
    if (q == 0 && threadIdx.x == 0) gcount[g] = len;
}

// ---------------- domain head: thread-per-output, no LDS ----------------

__global__ __launch_bounds__(256) void k_dom1(
    const float* __restrict__ pooled, const int* __restrict__ gcount,
    const float* __restrict__ W1, const float* __restrict__ b1,
    float* __restrict__ h1g)
{
    int o = blockIdx.x * 256 + threadIdx.x;       // 64*64 outputs
    if (o < 64 * 64) {
        int i = o >> 6, j = o & 63;
        float cnt = (float)gcount[i];
        float rc = 1.f / (cnt < 1.f ? 1.f : cnt);
        float s = b1[j];
        #pragma unroll 8
        for (int k = 0; k < 128; k++) s += pooled[i * 128 + k] * rc * W1[k * 64 + j];
        h1g[o] = s > 0.f ? s : (expf(s) - 1.f);
    }
}

__global__ __launch_bounds__(256) void k_dom2(
    const float* __restrict__ h1g,
    const float* __restrict__ W2, const float* __restrict__ b2,
    float* __restrict__ out)
{
    int o = blockIdx.x * 256 + threadIdx.x;       // 64*50 outputs
    if (o < 64 * N_PATIENTS) {
        int i = o / N_PATIENTS, p = o - i * N_PATIENTS;
        float s = b2[p];
        #pragma unroll 8
        for (int k = 0; k < 64; k++) s += h1g[i * 64 + k] * W2[k * N_PATIENTS + p];
        out[o] = s;
    }
}

// ---------------- launch ----------------

extern "C" void kernel_launch(void* const* d_in, const int* in_sizes, int n_in,
                              void* d_out, int out_size, void* d_ws, size_t ws_size,
                              hipStream_t stream) {
    const float* x     = (const float*)d_in[0];
    const int*   ei    = (const int*)d_in[1];
    const int*   batch = (const int*)d_in[2];
    const float* Wroot = (const float*)d_in[3];
    const float* Wrel  = (const float*)d_in[4];
    const float* bconv = (const float*)d_in[5];
    const float* gamma = (const float*)d_in[6];
    const float* beta  = (const float*)d_in[7];
    const float* bW    = (const float*)d_in[8];
    const float* bb    = (const float*)d_in[9];
    const float* W1    = (const float*)d_in[10];
    const float* b1    = (const float*)d_in[11];
    const float* W2    = (const float*)d_in[12];
    const float* b2    = (const float*)d_in[13];
    float* out = (float*)d_out;

    char* ws = (char*)d_ws;
    size_t off = 0;
    auto alloc = [&](size_t bytes) -> char* {
        char* p = ws + off;
        off += (bytes + 255) & ~(size_t)255;
        return p;
    };
    float*          xA      = (float*)alloc((size_t)N_NODES * DIM * 4);
    float*          xB      = (float*)alloc((size_t)N_NODES * DIM * 4);
    unsigned short* xbA     = (unsigned short*)alloc((size_t)N_NODES * DIM * 2);
    unsigned short* xbB     = (unsigned short*)alloc((size_t)N_NODES * DIM * 2);
    unsigned short* aggb    = (unsigned short*)alloc((size_t)N_NODES * DIM * 2);
    unsigned short* Wt      = (unsigned short*)alloc((size_t)NLAYERS * DIM * 256 * 2);
    int*            counts  = (int*)alloc((size_t)N_NODES * 4);
    int*            incl    = (int*)alloc((size_t)N_NODES * 4);
    int*            row_ptr = (int*)alloc((size_t)(N_NODES + 1) * 4);
    int*            cursor  = (int*)alloc((size_t)N_NODES * 4);
    int*            esorted = (int*)alloc((size_t)N_EDGES * 4);
    int*            bsums   = (int*)alloc(256 * 4);
    float*          pooled  = (float*)alloc((size_t)N_GRAPHS * DIM * 4);
    int*            gcount  = (int*)alloc((size_t)N_GRAPHS * 4);
    float*          h1g     = (float*)alloc((size_t)64 * 64 * 4);
    (void)ws_size; (void)in_sizes; (void)n_in; (void)out_size;

    hipMemsetAsync(counts, 0, (size_t)N_NODES * 4, stream);
    hipMemsetAsync(pooled, 0, (size_t)N_GRAPHS * DIM * 4, stream);

    k_wt<<<(NLAYERS * DIM * 256 + 255) / 256, 256, 0, stream>>>(Wroot, Wrel, Wt);
    k_prep<<<(N_NODES * DIM / 8 + 255) / 256, 256, 0, stream>>>(x, xbA);
    k_count<<<(N_EDGES + 255) / 256, 256, 0, stream>>>(ei, counts);
    int nb = (N_NODES + 255) / 256;
    k_scan_a<<<nb, 256, 0, stream>>>(counts, incl, bsums, N_NODES);
    k_scan_b<<<1, 256, 0, stream>>>(bsums, nb);
    k_scan_c<<<nb, 256, 0, stream>>>(counts, incl, bsums, row_ptr, cursor, N_NODES);
    k_fill<<<(N_EDGES + 255) / 256, 256, 0, stream>>>(ei, cursor, esorted);

    int agrid = (N_NODES + 15) / 16;
    int ggrid = (N_NODES + ROWS - 1) / ROWS;
    const float* xi = x;
    float* xo = xA;
    const unsigned short* xbi = xbA;
    unsigned short* xbo = xbB;
    for (int l = 0; l < NLAYERS; l++) {
        int last = (l == NLAYERS - 1);
        k_agg<<<agrid, 256, 0, stream>>>(xbi, aggb, row_ptr, esorted);
        k_gemm<<<ggrid, 512, 0, stream>>>(xi, aggb, xo, last ? nullptr : xbo,
                                          Wt + (size_t)l * DIM * 256,
                                          bconv + l * DIM, gamma + l * DIM, beta + l * DIM,
                                          bW, bb, out, last);
        xi = xo;
        xo = (xo == xA) ? xB : xA;
        const unsigned short* t = xbi; xbi = xbo; xbo = (unsigned short*)t;
    }
    k_pool<<<N_GRAPHS * 16, 256, 0, stream>>>(xi, batch, pooled, gcount);
    k_dom1<<<16, 256, 0, stream>>>(pooled, gcount, W1, b1, h1g);
    k_dom2<<<(64 * N_PATIENTS + 255) / 256, 256, 0, stream>>>(h1g, W2, b2, out + N_NODES);
}

// Round 10
// 366.508 us; speedup vs baseline: 1.0286x; 1.0286x over previous
//
#include <hip/hip_runtime.h>
#include <cstdint>
#include <cstddef>

#define N_NODES   50000
#define N_EDGES   600000
#define DIM       128
#define NLAYERS   4
#define N_GRAPHS  64
#define N_PATIENTS 50
#define ROWS      32

typedef __attribute__((ext_vector_type(8))) __bf16        bf16x8;
typedef __attribute__((ext_vector_type(4))) float         f32x4;
typedef __attribute__((ext_vector_type(4))) unsigned int  u32x4;
typedef __attribute__((ext_vector_type(8))) unsigned short u16x8;

__device__ inline unsigned short f2bf(float f) {
    unsigned u = __builtin_bit_cast(unsigned, f);
    u += 0x7FFFu + ((u >> 16) & 1u);   // round-to-nearest-even
    return (unsigned short)(u >> 16);
}

__device__ inline float bf2f(unsigned short s) {
    return __builtin_bit_cast(float, (unsigned)s << 16);
}

__device__ inline f32x4 lo4(u16x8 u) {
    f32x4 r;
    r[0] = bf2f(u[0]); r[1] = bf2f(u[1]); r[2] = bf2f(u[2]); r[3] = bf2f(u[3]);
    return r;
}
__device__ inline f32x4 hi4(u16x8 u) {
    f32x4 r;
    r[0] = bf2f(u[4]); r[1] = bf2f(u[5]); r[2] = bf2f(u[6]); r[3] = bf2f(u[7]);
    return r;
}

// ---------------- CSR build ----------------

__global__ void k_count(const int* __restrict__ ei, int* __restrict__ counts) {
    int e = blockIdx.x * 256 + threadIdx.x;
    if (e < N_EDGES) atomicAdd(&counts[ei[N_EDGES + e]], 1);
}

__global__ void k_scan_a(const int* __restrict__ counts, int* __restrict__ incl,
                         int* __restrict__ bsums, int n) {
    __shared__ int s[256];
    int i = blockIdx.x * 256 + threadIdx.x;
    int v = (i < n) ? counts[i] : 0;
    s[threadIdx.x] = v;
    __syncthreads();
    for (int off = 1; off < 256; off <<= 1) {
        int t = (threadIdx.x >= off) ? s[threadIdx.x - off] : 0;
        __syncthreads();
        s[threadIdx.x] += t;
        __syncthreads();
    }
    if (i < n) incl[i] = s[threadIdx.x];
    if (threadIdx.x == 255) bsums[blockIdx.x] = s[255];
}

__global__ void k_scan_b(int* __restrict__ bsums, int nb) {
    __shared__ int s[256];
    int t = threadIdx.x;
    int v = (t < nb) ? bsums[t] : 0;
    s[t] = v;
    __syncthreads();
    for (int off = 1; off < 256; off <<= 1) {
        int u = (t >= off) ? s[t - off] : 0;
        __syncthreads();
        s[t] += u;
        __syncthreads();
    }
    if (t < nb) bsums[t] = s[t];
}

__global__ void k_scan_c(const int* __restrict__ counts, const int* __restrict__ incl,
                         const int* __restrict__ bsums, int* __restrict__ row_ptr,
                         int* __restrict__ cursor, int n) {
    int i = blockIdx.x * 256 + threadIdx.x;
    if (i < n) {
        int off = blockIdx.x ? bsums[blockIdx.x - 1] : 0;
        int ex  = incl[i] - counts[i] + off;
        row_ptr[i] = ex;
        cursor[i]  = ex;
        if (i == n - 1) row_ptr[n] = incl[i] + off;
    }
}

__global__ void k_fill(const int* __restrict__ ei, int* __restrict__ cursor,
                       int* __restrict__ esorted) {
    int e = blockIdx.x * 256 + threadIdx.x;
    if (e < N_EDGES) {
        int d   = ei[N_EDGES + e];
        int pos = atomicAdd(&cursor[d], 1);
        esorted[pos] = ei[e];
    }
}

// ---------------- x -> bf16 mirror (layer 0) ----------------

__global__ void k_prep(const float* __restrict__ x, unsigned short* __restrict__ xb) {
    int idx = blockIdx.x * 256 + threadIdx.x;        // one u16x8 per thread
    if (idx < N_NODES * DIM / 8) {
        f32x4 v0 = *(const f32x4*)(x + (size_t)idx * 8);
        f32x4 v1 = *(const f32x4*)(x + (size_t)idx * 8 + 4);
        u16x8 o = { f2bf(v0[0]), f2bf(v0[1]), f2bf(v0[2]), f2bf(v0[3]),
                    f2bf(v1[0]), f2bf(v1[1]), f2bf(v1[2]), f2bf(v1[3]) };
        *(u16x8*)(xb + (size_t)idx * 8) = o;
    }
}

// ---------------- W precombine: Wt[l][c][k] = bf16(Wcat[k][c]) ----------------

__global__ void k_wt(const float* __restrict__ Wroot, const float* __restrict__ Wrel,
                     unsigned short* __restrict__ Wt) {
    int idx = blockIdx.x * 256 + threadIdx.x;   // l*32768 + c*256 + k
    if (idx < NLAYERS * DIM * 256) {
        int l = idx >> 15;
        int c = (idx >> 8) & 127;
        int k = idx & 255;
        float v = (k < 128) ? Wroot[l * 16384 + k * 128 + c]
                            : Wrel[l * 16384 + (k - 128) * 128 + c];
        Wt[idx] = f2bf(v);
    }
}

// ---------------- fused layer (512 threads, 32 rows, f32 carry + bf16 mirror) ----------------

__global__ __launch_bounds__(512, 6) void k_layer(
    const float* __restrict__ xin,                // f32 x (residual source)
    const unsigned short* __restrict__ xb,        // bf16 mirror of xin (gather + A-tile)
    float* __restrict__ xout,                     // f32 x out
    unsigned short* __restrict__ xbnext,          // bf16 mirror out (null on last layer)
    const int* __restrict__ row_ptr, const int* __restrict__ esrc,
    const unsigned short* __restrict__ Wt,        // [128][256] bf16, linear
    const float* __restrict__ bconv, const float* __restrict__ gamma,
    const float* __restrict__ beta,
    const float* __restrict__ bW, const float* __restrict__ bb,
    float* __restrict__ boundary, int last)
{
    __shared__ __align__(16) unsigned short x2s[ROWS * 256];   // 16 KB, XOR-swizzled
    __shared__ float rsum[ROWS][4], rsq[ROWS][4], rbl[ROWS][4];
    const int tid     = threadIdx.x;
    const int rowbase = blockIdx.x * ROWS;
    const int lane = tid & 63, w = tid >> 6;

    // decomposition shared by phase 1a/1b: 16-lane group per row
    const int grp = tid >> 4;          // 0..31 == local row
    const int li  = tid & 15;          // 16B slice within the 256B row

    // phase 1a: x row (bf16 mirror) -> LDS cols [0,128)
    {
        int grow = rowbase + grp;
        int rx = (grp & 7) << 4;
        u16x8 v = { 0, 0, 0, 0, 0, 0, 0, 0 };
        if (grow < N_NODES) v = *(const u16x8*)(xb + (size_t)grow * DIM + li * 8);
        int byteoff = (grp * 512 + li * 16) ^ rx;
        *(u16x8*)((char*)x2s + byteoff) = v;
    }

    // phase 1b: CSR neighbor-sum -> LDS cols [128,256).
    // One row per 16-lane group (full 256B row: 16 lanes x 16B), 6-edge unroll.
    {
        int grow = rowbase + grp;
        f32x4 a0 = 0.f, a1 = 0.f, b0 = 0.f, b1 = 0.f;
        int beg = 0, end = 0;
        if (grow < N_NODES) { beg = row_ptr[grow]; end = row_ptr[grow + 1]; }
        int e = beg;
        for (; e + 5 < end; e += 6) {
            int s0 = esrc[e],     s1 = esrc[e + 1], s2 = esrc[e + 2];
            int s3 = esrc[e + 3], s4 = esrc[e + 4], s5 = esrc[e + 5];
            u16x8 u0 = *(const u16x8*)(xb + (size_t)s0 * DIM + li * 8);
            u16x8 u1 = *(const u16x8*)(xb + (size_t)s1 * DIM + li * 8);
            u16x8 u2 = *(const u16x8*)(xb + (size_t)s2 * DIM + li * 8);
            u16x8 u3 = *(const u16x8*)(xb + (size_t)s3 * DIM + li * 8);
            u16x8 u4 = *(const u16x8*)(xb + (size_t)s4 * DIM + li * 8);
            u16x8 u5 = *(const u16x8*)(xb + (size_t)s5 * DIM + li * 8);
            a0 += lo4(u0); a1 += hi4(u0);
            b0 += lo4(u1); b1 += hi4(u1);
            a0 += lo4(u2); a1 += hi4(u2);
            b0 += lo4(u3); b1 += hi4(u3);
            a0 += lo4(u4); a1 += hi4(u4);
            b0 += lo4(u5); b1 += hi4(u5);
        }
        for (; e < end; ++e) {
            int s0 = esrc[e];
            u16x8 u0 = *(const u16x8*)(xb + (size_t)s0 * DIM + li * 8);
            a0 += lo4(u0); a1 += hi4(u0);
        }
        a0 += b0; a1 += b1;
        u16x8 o = { f2bf(a0[0]), f2bf(a0[1]), f2bf(a0[2]), f2bf(a0[3]),
                    f2bf(a1[0]), f2bf(a1[1]), f2bf(a1[2]), f2bf(a1[3]) };
        int byteoff = (grp * 512 + 256 + li * 16) ^ ((grp & 7) << 4);
        *(u16x8*)((char*)x2s + byteoff) = o;
    }
    __syncthreads();

    // phase 2: [32x256] @ [256x128]. Wave w: rowtile rt = w>>2, colquarter cq = w&3.
    int colb = lane & 15, kg = lane >> 4;
    int rt = w >> 2, cq = w & 3;

    u32x4 araw[8];
    {
        int row  = rt * 16 + colb;
        int base = row * 512 + kg * 16;
        int rx   = (row & 7) << 4;
        #pragma unroll
        for (int ks = 0; ks < 8; ks++) {
            int byteoff = (base + ks * 64) ^ rx;
            araw[ks] = *(const u32x4*)((const char*)x2s + byteoff);
        }
    }

    f32x4 acc[2];
    acc[0] = 0.0f; acc[1] = 0.0f;

    #pragma unroll
    for (int cb = 0; cb < 2; cb++) {
        const unsigned short* wp = Wt + ((cq * 32 + cb * 16 + colb) * 256 + kg * 8);
        #pragma unroll
        for (int ks = 0; ks < 8; ks++) {
            u32x4 braw = *(const u32x4*)(wp + ks * 32);
            acc[cb] = __builtin_amdgcn_mfma_f32_16x16x32_bf16(
                __builtin_bit_cast(bf16x8, araw[ks]),
                __builtin_bit_cast(bf16x8, braw), acc[cb], 0, 0, 0);
        }
    }

    // epilogue part 1: per-row partial sums (32 cols per wave) -> LDS slots
    float hv[4][2];
    #pragma unroll
    for (int j = 0; j < 4; j++) {
        float ps = 0.f, pq = 0.f;
        #pragma unroll
        for (int cb = 0; cb < 2; cb++) {
            int col = cq * 32 + cb * 16 + colb;
            float h = acc[cb][j] + bconv[col];
            hv[j][cb] = h; ps += h; pq += h * h;
        }
        #pragma unroll
        for (int m = 1; m < 16; m <<= 1) {
            ps += __shfl_xor(ps, m);
            pq += __shfl_xor(pq, m);
        }
        if (colb == 0) {
            int lr = rt * 16 + kg * 4 + j;
            rsum[lr][cq] = ps;
            rsq[lr][cq]  = pq;
        }
    }
    __syncthreads();

    // epilogue part 2: LN, ELU, residual from f32 xin (L1/L2-hit), stores, boundary
    #pragma unroll
    for (int j = 0; j < 4; j++) {
        int lr   = rt * 16 + kg * 4 + j;
        int grow = rowbase + lr;
        float sum = rsum[lr][0] + rsum[lr][1] + rsum[lr][2] + rsum[lr][3];
        float sq  = rsq[lr][0] + rsq[lr][1] + rsq[lr][2] + rsq[lr][3];
        float mean = sum * (1.f / 128.f);
        float var  = sq * (1.f / 128.f) - mean * mean;
        float rs   = rsqrtf(var + 1e-5f);
        float bl = 0.f;
        if (grow < N_NODES) {
            #pragma unroll
            for (int cb = 0; cb < 2; cb++) {
                int col  = cq * 32 + cb * 16 + colb;
                float hn = (hv[j][cb] - mean) * rs * gamma[col] + beta[col];
                hn = hn > 0.f ? hn : (expf(hn) - 1.f);
                float xo = hn + xin[(size_t)grow * DIM + col];
                xout[(size_t)grow * DIM + col] = xo;
                if (xbnext) xbnext[(size_t)grow * DIM + col] = f2bf(xo);
                bl += xo * bW[col];
            }
        }
        if (last) {
            #pragma unroll
            for (int m = 1; m < 16; m <<= 1) bl += __shfl_xor(bl, m);
            if (colb == 0) rbl[lr][cq] = bl;
        }
    }
    if (last) {
        __syncthreads();
        if (tid < ROWS && rowbase + tid < N_NODES)
            boundary[rowbase + tid] = rbl[tid][0] + rbl[tid][1] + rbl[tid][2] + rbl[tid][3] + bb[0];
    }
}

// ---------------- mean-pool per graph (batch is sorted, x f32) ----------------

__global__ void k_pool(const float* __restrict__ x, const int* __restrict__ batch,
                       float* __restrict__ pooled, int* __restrict__ gcount) {
    __shared__ float s[128];
    int g = blockIdx.x >> 4, q = blockIdx.x & 15;
    int lo = 0, hi = N_NODES;
    while (lo < hi) { int m = (lo + hi) >> 1; if (batch[m] < g) lo = m + 1; else hi = m; }
    int s0 = lo;
    lo = 0; hi = N_NODES;
    while (lo < hi) { int m = (lo + hi) >> 1; if (batch[m] < g + 1) lo = m + 1; else hi = m; }
    int e0  = lo;
    int len = e0 - s0;
    int r0 = s0 + (int)((long long)len * q / 16);
    int r1 = s0 + (int)((long long)len * (q + 1) / 16);
    int col = threadIdx.x & 127, half = threadIdx.x >> 7;
    float acc = 0.f;
    for (int r = r0 + half; r < r1; r += 2) acc += x[(size_t)r * DIM + col];
    if (half) s[col] = acc;
    __syncthreads();
    if (!half) {
        acc += s[col];
        atomicAdd(&pooled[g * DIM + col], acc);
    }
    if (q == 0 && threadIdx.x == 0) gcount[g] = len;
}

// ---------------- domain head: thread-per-output, no LDS ----------------

__global__ __launch_bounds__(256) void k_dom1(
    const float* __restrict__ pooled, const int* __restrict__ gcount,
    const float* __restrict__ W1, const float* __restrict__ b1,
    float* __restrict__ h1g)
{
    int o = blockIdx.x * 256 + threadIdx.x;       // 64*64 outputs
    if (o < 64 * 64) {
        int i = o >> 6, j = o & 63;
        float cnt = (float)gcount[i];
        float rc = 1.f / (cnt < 1.f ? 1.f : cnt);
        float s = b1[j];
        #pragma unroll 8
        for (int k = 0; k < 128; k++) s += pooled[i * 128 + k] * rc * W1[k * 64 + j];
        h1g[o] = s > 0.f ? s : (expf(s) - 1.f);
    }
}

__global__ __launch_bounds__(256) void k_dom2(
    const float* __restrict__ h1g,
    const float* __restrict__ W2, const float* __restrict__ b2,
    float* __restrict__ out)
{
    int o = blockIdx.x * 256 + threadIdx.x;       // 64*50 outputs
    if (o < 64 * N_PATIENTS) {
        int i = o / N_PATIENTS, p = o - i * N_PATIENTS;
        float s = b2[p];
        #pragma unroll 8
        for (int k = 0; k < 64; k++) s += h1g[i * 64 + k] * W2[k * N_PATIENTS + p];
        out[o] = s;
    }
}

// ---------------- launch ----------------

extern "C" void kernel_launch(void* const* d_in, const int* in_sizes, int n_in,
                              void* d_out, int out_size, void* d_ws, size_t ws_size,
                              hipStream_t stream) {
    const float* x     = (const float*)d_in[0];
    const int*   ei    = (const int*)d_in[1];
    const int*   batch = (const int*)d_in[2];
    const float* Wroot = (const float*)d_in[3];
    const float* Wrel  = (const float*)d_in[4];
    const float* bconv = (const float*)d_in[5];
    const float* gamma = (const float*)d_in[6];
    const float* beta  = (const float*)d_in[7];
    const float* bW    = (const float*)d_in[8];
    const float* bb    = (const float*)d_in[9];
    const float* W1    = (const float*)d_in[10];
    const float* b1    = (const float*)d_in[11];
    const float* W2    = (const float*)d_in[12];
    const float* b2    = (const float*)d_in[13];
    float* out = (float*)d_out;

    char* ws = (char*)d_ws;
    size_t off = 0;
    auto alloc = [&](size_t bytes) -> char* {
        char* p = ws + off;
        off += (bytes + 255) & ~(size_t)255;
        return p;
    };
    float*          xA      = (float*)alloc((size_t)N_NODES * DIM * 4);
    float*          xB      = (float*)alloc((size_t)N_NODES * DIM * 4);
    unsigned short* xbA     = (unsigned short*)alloc((size_t)N_NODES * DIM * 2);
    unsigned short* xbB     = (unsigned short*)alloc((size_t)N_NODES * DIM * 2);
    unsigned short* Wt      = (unsigned short*)alloc((size_t)NLAYERS * DIM * 256 * 2);
    int*            counts  = (int*)alloc((size_t)N_NODES * 4);
    int*            incl    = (int*)alloc((size_t)N_NODES * 4);
    int*            row_ptr = (int*)alloc((size_t)(N_NODES + 1) * 4);
    int*            cursor  = (int*)alloc((size_t)N_NODES * 4);
    int*            esorted = (int*)alloc((size_t)N_EDGES * 4);
    int*            bsums   = (int*)alloc(256 * 4);
    float*          pooled  = (float*)alloc((size_t)N_GRAPHS * DIM * 4);
    int*            gcount  = (int*)alloc((size_t)N_GRAPHS * 4);
    float*          h1g     = (float*)alloc((size_t)64 * 64 * 4);
    (void)ws_size; (void)in_sizes; (void)n_in; (void)out_size;

    hipMemsetAsync(counts, 0, (size_t)N_NODES * 4, stream);
    hipMemsetAsync(pooled, 0, (size_t)N_GRAPHS * DIM * 4, stream);

    k_wt<<<(NLAYERS * DIM * 256 + 255) / 256, 256, 0, stream>>>(Wroot, Wrel, Wt);
    k_prep<<<(N_NODES * DIM / 8 + 255) / 256, 256, 0, stream>>>(x, xbA);
    k_count<<<(N_EDGES + 255) / 256, 256, 0, stream>>>(ei, counts);
    int nb = (N_NODES + 255) / 256;
    k_scan_a<<<nb, 256, 0, stream>>>(counts, incl, bsums, N_NODES);
    k_scan_b<<<1, 256, 0, stream>>>(bsums, nb);
    k_scan_c<<<nb, 256, 0, stream>>>(counts, incl, bsums, row_ptr, cursor, N_NODES);
    k_fill<<<(N_EDGES + 255) / 256, 256, 0, stream>>>(ei, cursor, esorted);

    int lgrid = (N_NODES + ROWS - 1) / ROWS;
    const float* xi = x;
    float* xo = xA;
    const unsigned short* xbi = xbA;
    unsigned short* xbo = xbB;
    for (int l = 0; l < NLAYERS; l++) {
        int last = (l == NLAYERS - 1);
        k_layer<<<lgrid, 512, 0, stream>>>(xi, xbi, xo, last ? nullptr : xbo,
                                           row_ptr, esorted, Wt + (size_t)l * DIM * 256,
                                           bconv + l * DIM, gamma + l * DIM, beta + l * DIM,
                                           bW, bb, out, last);
        xi = xo;
        xo = (xo == xA) ? xB : xA;
        const unsigned short* t = xbi; xbi = xbo; xbo = (unsigned short*)t;
    }
    k_pool<<<N_GRAPHS * 16, 256, 0, stream>>>(xi, batch, pooled, gcount);
    k_dom1<<<16, 256, 0, stream>>>(pooled, gcount, W1, b1, h1g);
    k_dom2<<<(64 * N_PATIENTS + 255) / 256, 256, 0, stream>>>(h1g, W2, b2, out + N_NODES);
}

// Round 11
// 332.851 us; speedup vs baseline: 1.1326x; 1.1011x over previous
//
#include <hip/hip_runtime.h>
#include <cstdint>
#include <cstddef>

#define N_NODES   50000
#define N_EDGES   600000
#define DIM       128
#define NLAYERS   4
#define N_GRAPHS  64
#define N_PATIENTS 50
#define ROWS      32

typedef __attribute__((ext_vector_type(8))) __bf16        bf16x8;
typedef __attribute__((ext_vector_type(4))) float         f32x4;
typedef __attribute__((ext_vector_type(4))) unsigned int  u32x4;
typedef __attribute__((ext_vector_type(8))) unsigned short u16x8;

__device__ inline unsigned short f2bf(float f) {
    unsigned u = __builtin_bit_cast(unsigned, f);
    u += 0x7FFFu + ((u >> 16) & 1u);   // round-to-nearest-even
    return (unsigned short)(u >> 16);
}

__device__ inline float bf2f(unsigned short s) {
    return __builtin_bit_cast(float, (unsigned)s << 16);
}

__device__ inline f32x4 lo4(u16x8 u) {
    f32x4 r;
    r[0] = bf2f(u[0]); r[1] = bf2f(u[1]); r[2] = bf2f(u[2]); r[3] = bf2f(u[3]);
    return r;
}
__device__ inline f32x4 hi4(u16x8 u) {
    f32x4 r;
    r[0] = bf2f(u[4]); r[1] = bf2f(u[5]); r[2] = bf2f(u[6]); r[3] = bf2f(u[7]);
    return r;
}

// ---------------- CSR build ----------------

__global__ void k_count(const int* __restrict__ ei, int* __restrict__ counts) {
    int e = blockIdx.x * 256 + threadIdx.x;
    if (e < N_EDGES) atomicAdd(&counts[ei[N_EDGES + e]], 1);
}

__global__ void k_scan_a(const int* __restrict__ counts, int* __restrict__ incl,
                         int* __restrict__ bsums, int n) {
    __shared__ int s[256];
    int i = blockIdx.x * 256 + threadIdx.x;
    int v = (i < n) ? counts[i] : 0;
    s[threadIdx.x] = v;
    __syncthreads();
    for (int off = 1; off < 256; off <<= 1) {
        int t = (threadIdx.x >= off) ? s[threadIdx.x - off] : 0;
        __syncthreads();
        s[threadIdx.x] += t;
        __syncthreads();
    }
    if (i < n) incl[i] = s[threadIdx.x];
    if (threadIdx.x == 255) bsums[blockIdx.x] = s[255];
}

__global__ void k_scan_b(int* __restrict__ bsums, int nb) {
    __shared__ int s[256];
    int t = threadIdx.x;
    int v = (t < nb) ? bsums[t] : 0;
    s[t] = v;
    __syncthreads();
    for (int off = 1; off < 256; off <<= 1) {
        int u = (t >= off) ? s[t - off] : 0;
        __syncthreads();
        s[t] += u;
        __syncthreads();
    }
    if (t < nb) bsums[t] = s[t];
}

__global__ void k_scan_c(const int* __restrict__ counts, const int* __restrict__ incl,
                         const int* __restrict__ bsums, int* __restrict__ row_ptr,
                         int* __restrict__ cursor, int n) {
    int i = blockIdx.x * 256 + threadIdx.x;
    if (i < n) {
        int off = blockIdx.x ? bsums[blockIdx.x - 1] : 0;
        int ex  = incl[i] - counts[i] + off;
        row_ptr[i] = ex;
        cursor[i]  = ex;
        if (i == n - 1) row_ptr[n] = incl[i] + off;
    }
}

__global__ void k_fill(const int* __restrict__ ei, int* __restrict__ cursor,
                       int* __restrict__ esorted) {
    int e = blockIdx.x * 256 + threadIdx.x;
    if (e < N_EDGES) {
        int d   = ei[N_EDGES + e];
        int pos = atomicAdd(&cursor[d], 1);
        esorted[pos] = ei[e];
    }
}

// ---------------- x -> (hi, lo) bf16 pair + W precombine (fused) ----------------

__global__ void k_prep(const float* __restrict__ x,
                       unsigned short* __restrict__ xhi, unsigned short* __restrict__ xlo,
                       const float* __restrict__ Wroot, const float* __restrict__ Wrel,
                       unsigned short* __restrict__ Wt) {
    int idx = blockIdx.x * 256 + threadIdx.x;        // one u16x8 per thread
    if (idx < N_NODES * DIM / 8) {
        f32x4 v0 = *(const f32x4*)(x + (size_t)idx * 8);
        f32x4 v1 = *(const f32x4*)(x + (size_t)idx * 8 + 4);
        u16x8 h, l;
        #pragma unroll
        for (int j = 0; j < 4; j++) {
            unsigned short hh = f2bf(v0[j]);
            h[j] = hh; l[j] = f2bf(v0[j] - bf2f(hh));
        }
        #pragma unroll
        for (int j = 0; j < 4; j++) {
            unsigned short hh = f2bf(v1[j]);
            h[4 + j] = hh; l[4 + j] = f2bf(v1[j] - bf2f(hh));
        }
        *(u16x8*)(xhi + (size_t)idx * 8) = h;
        *(u16x8*)(xlo + (size_t)idx * 8) = l;
    }
    if (idx < NLAYERS * DIM * 256) {                 // Wt[l][c][k] = bf16(Wcat[k][c])
        int l = idx >> 15;
        int c = (idx >> 8) & 127;
        int k = idx & 255;
        float v = (k < 128) ? Wroot[l * 16384 + k * 128 + c]
                            : Wrel[l * 16384 + (k - 128) * 128 + c];
        Wt[idx] = f2bf(v);
    }
}

// ---------------- fused layer (512 threads, 32 rows, bf16-pair carry) ----------------

__global__ __launch_bounds__(512, 8) void k_layer(
    const unsigned short* __restrict__ xhi,       // bf16 high part (gather + A-tile)
    const unsigned short* __restrict__ xlo,       // bf16 low part (residual correction)
    unsigned short* __restrict__ xhi_o,
    unsigned short* __restrict__ xlo_o,
    const int* __restrict__ row_ptr, const int* __restrict__ esrc,
    const unsigned short* __restrict__ Wt,        // [128][256] bf16, linear
    const float* __restrict__ bconv, const float* __restrict__ gamma,
    const float* __restrict__ beta,
    const float* __restrict__ bW, const float* __restrict__ bb,
    float* __restrict__ boundary, int last)
{
    __shared__ __align__(16) unsigned short x2s[ROWS * 256];   // 16 KB, XOR-swizzled
    __shared__ __align__(16) unsigned short e2s[ROWS][136];    // 8.7 KB, padded (272B row, 16B-aligned)
    __shared__ float rsum[ROWS][4], rsq[ROWS][4], rbl[ROWS][4];
    const int tid     = threadIdx.x;
    const int rowbase = blockIdx.x * ROWS;
    const int lane = tid & 63, w = tid >> 6;

    // decomposition shared by phase 1a/1b: 16-lane group per row
    const int grp = tid >> 4;          // 0..31 == local row
    const int li  = tid & 15;          // 16B slice within the 256B row

    // phase 1a: hi row -> LDS A-tile cols [0,128); lo row -> e2s
    {
        int grow = rowbase + grp;
        int rx = (grp & 7) << 4;
        u16x8 v = { 0, 0, 0, 0, 0, 0, 0, 0 };
        u16x8 ev = { 0, 0, 0, 0, 0, 0, 0, 0 };
        if (grow < N_NODES) {
            v  = *(const u16x8*)(xhi + (size_t)grow * DIM + li * 8);
            ev = *(const u16x8*)(xlo + (size_t)grow * DIM + li * 8);
        }
        int byteoff = (grp * 512 + li * 16) ^ rx;
        *(u16x8*)((char*)x2s + byteoff) = v;
        *(u16x8*)(&e2s[grp][li * 8]) = ev;
    }

    // phase 1b: CSR neighbor-sum over hi -> LDS cols [128,256).
    // One row per 16-lane group (full 256B row: 16 lanes x 16B), 6-edge unroll.
    {
        int grow = rowbase + grp;
        f32x4 a0 = 0.f, a1 = 0.f, b0 = 0.f, b1 = 0.f;
        int beg = 0, end = 0;
        if (grow < N_NODES) { beg = row_ptr[grow]; end = row_ptr[grow + 1]; }
        int e = beg;
        for (; e + 5 < end; e += 6) {
            int s0 = esrc[e],     s1 = esrc[e + 1], s2 = esrc[e + 2];
            int s3 = esrc[e + 3], s4 = esrc[e + 4], s5 = esrc[e + 5];
            u16x8 u0 = *(const u16x8*)(xhi + (size_t)s0 * DIM + li * 8);
            u16x8 u1 = *(const u16x8*)(xhi + (size_t)s1 * DIM + li * 8);
            u16x8 u2 = *(const u16x8*)(xhi + (size_t)s2 * DIM + li * 8);
            u16x8 u3 = *(const u16x8*)(xhi + (size_t)s3 * DIM + li * 8);
            u16x8 u4 = *(const u16x8*)(xhi + (size_t)s4 * DIM + li * 8);
            u16x8 u5 = *(const u16x8*)(xhi + (size_t)s5 * DIM + li * 8);
            a0 += lo4(u0); a1 += hi4(u0);
            b0 += lo4(u1); b1 += hi4(u1);
            a0 += lo4(u2); a1 += hi4(u2);
            b0 += lo4(u3); b1 += hi4(u3);
            a0 += lo4(u4); a1 += hi4(u4);
            b0 += lo4(u5); b1 += hi4(u5);
        }
        for (; e < end; ++e) {
            int s0 = esrc[e];
            u16x8 u0 = *(const u16x8*)(xhi + (size_t)s0 * DIM + li * 8);
            a0 += lo4(u0); a1 += hi4(u0);
        }
        a0 += b0; a1 += b1;
        u16x8 o = { f2bf(a0[0]), f2bf(a0[1]), f2bf(a0[2]), f2bf(a0[3]),
                    f2bf(a1[0]), f2bf(a1[1]), f2bf(a1[2]), f2bf(a1[3]) };
        int byteoff = (grp * 512 + 256 + li * 16) ^ ((grp & 7) << 4);
        *(u16x8*)((char*)x2s + byteoff) = o;
    }
    __syncthreads();

    // phase 2: [32x256] @ [256x128]. Wave w: rowtile rt = w>>2, colquarter cq = w&3.
    int colb = lane & 15, kg = lane >> 4;
    int rt = w >> 2, cq = w & 3;

    u32x4 araw[8];
    {
        int row  = rt * 16 + colb;
        int base = row * 512 + kg * 16;
        int rx   = (row & 7) << 4;
        #pragma unroll
        for (int ks = 0; ks < 8; ks++) {
            int byteoff = (base + ks * 64) ^ rx;
            araw[ks] = *(const u32x4*)((const char*)x2s + byteoff);
        }
    }

    f32x4 acc[2];
    acc[0] = 0.0f; acc[1] = 0.0f;

    #pragma unroll
    for (int cb = 0; cb < 2; cb++) {
        const unsigned short* wp = Wt + ((cq * 32 + cb * 16 + colb) * 256 + kg * 8);
        #pragma unroll
        for (int ks = 0; ks < 8; ks++) {
            u32x4 braw = *(const u32x4*)(wp + ks * 32);
            acc[cb] = __builtin_amdgcn_mfma_f32_16x16x32_bf16(
                __builtin_bit_cast(bf16x8, araw[ks]),
                __builtin_bit_cast(bf16x8, braw), acc[cb], 0, 0, 0);
        }
    }

    // epilogue part 1: per-row partial sums (32 cols per wave) -> LDS slots
    float hv[4][2];
    #pragma unroll
    for (int j = 0; j < 4; j++) {
        float ps = 0.f, pq = 0.f;
        #pragma unroll
        for (int cb = 0; cb < 2; cb++) {
            int col = cq * 32 + cb * 16 + colb;
            float h = acc[cb][j] + bconv[col];
            hv[j][cb] = h; ps += h; pq += h * h;
        }
        #pragma unroll
        for (int m = 1; m < 16; m <<= 1) {
            ps += __shfl_xor(ps, m);
            pq += __shfl_xor(pq, m);
        }
        if (colb == 0) {
            int lr = rt * 16 + kg * 4 + j;
            rsum[lr][cq] = ps;
            rsq[lr][cq]  = pq;
        }
    }
    __syncthreads();

    // epilogue part 2: LN, ELU, residual = bf2f(hi)+bf2f(lo) from LDS, pair store
    #pragma unroll
    for (int j = 0; j < 4; j++) {
        int lr   = rt * 16 + kg * 4 + j;
        int grow = rowbase + lr;
        float sum = rsum[lr][0] + rsum[lr][1] + rsum[lr][2] + rsum[lr][3];
        float sq  = rsq[lr][0] + rsq[lr][1] + rsq[lr][2] + rsq[lr][3];
        float mean = sum * (1.f / 128.f);
        float var  = sq * (1.f / 128.f) - mean * mean;
        float rs   = rsqrtf(var + 1e-5f);
        float bl = 0.f;
        if (grow < N_NODES) {
            int rx = (lr & 7) << 4;
            #pragma unroll
            for (int cb = 0; cb < 2; cb++) {
                int col  = cq * 32 + cb * 16 + colb;
                float hn = (hv[j][cb] - mean) * rs * gamma[col] + beta[col];
                hn = hn > 0.f ? hn : (expf(hn) - 1.f);
                int hoff = (lr * 512 + col * 2) ^ rx;
                float xi = bf2f(*(const unsigned short*)((const char*)x2s + hoff))
                         + bf2f(e2s[lr][col]);
                float xo = hn + xi;
                unsigned short ho = f2bf(xo);
                xhi_o[(size_t)grow * DIM + col] = ho;
                xlo_o[(size_t)grow * DIM + col] = f2bf(xo - bf2f(ho));
                bl += xo * bW[col];
            }
        }
        if (last) {
            #pragma unroll
            for (int m = 1; m < 16; m <<= 1) bl += __shfl_xor(bl, m);
            if (colb == 0) rbl[lr][cq] = bl;
        }
    }
    if (last) {
        __syncthreads();
        if (tid < ROWS && rowbase + tid < N_NODES)
            boundary[rowbase + tid] = rbl[tid][0] + rbl[tid][1] + rbl[tid][2] + rbl[tid][3] + bb[0];
    }
}

// ---------------- mean-pool per graph (batch sorted, x = hi+lo) ----------------

__global__ void k_pool(const unsigned short* __restrict__ xhi,
                       const unsigned short* __restrict__ xlo,
                       const int* __restrict__ batch,
                       float* __restrict__ pooled, int* __restrict__ gcount) {
    __shared__ float2 s[64][4];
    int g = blockIdx.x >> 4, q = blockIdx.x & 15;
    int lo = 0, hi = N_NODES;
    while (lo < hi) { int m = (lo + hi) >> 1; if (batch[m] < g) lo = m + 1; else hi = m; }
    int s0 = lo;
    lo = 0; hi = N_NODES;
    while (lo < hi) { int m = (lo + hi) >> 1; if (batch[m] < g + 1) lo = m + 1; else hi = m; }
    int e0  = lo;
    int len = e0 - s0;
    int r0 = s0 + (int)((long long)len * q / 16);
    int r1 = s0 + (int)((long long)len * (q + 1) / 16);
    int cp = threadIdx.x & 63, rp = threadIdx.x >> 6;     // col pair, 4-way row split
    float ax = 0.f, ay = 0.f;
    for (int r = r0 + rp; r < r1; r += 4) {
        unsigned uh = *(const unsigned*)(xhi + (size_t)r * DIM + cp * 2);
        unsigned ul = *(const unsigned*)(xlo + (size_t)r * DIM + cp * 2);
        ax += bf2f((unsigned short)(uh & 0xFFFF)) + bf2f((unsigned short)(ul & 0xFFFF));
        ay += bf2f((unsigned short)(uh >> 16)) + bf2f((unsigned short)(ul >> 16));
    }
    s[cp][rp] = make_float2(ax, ay);
    __syncthreads();
    if (rp == 0) {
        float2 v1 = s[cp][1], v2 = s[cp][2], v3 = s[cp][3];
        ax += v1.x + v2.x + v3.x;
        ay += v1.y + v2.y + v3.y;
        atomicAdd(&pooled[g * DIM + cp * 2], ax);
        atomicAdd(&pooled[g * DIM + cp * 2 + 1], ay);
    }
    if (q == 0 && threadIdx.x == 0) gcount[g] = len;
}

// ---------------- domain head: thread-per-output, no LDS ----------------

__global__ __launch_bounds__(256) void k_dom1(
    const float* __restrict__ pooled, const int* __restrict__ gcount,
    const float* __restrict__ W1, const float* __restrict__ b1,
    float* __restrict__ h1g)
{
    int o = blockIdx.x * 256 + threadIdx.x;       // 64*64 outputs
    if (o < 64 * 64) {
        int i = o >> 6, j = o & 63;
        float cnt = (float)gcount[i];
        float rc = 1.f / (cnt < 1.f ? 1.f : cnt);
        float s = b1[j];
        #pragma unroll 8
        for (int k = 0; k < 128; k++) s += pooled[i * 128 + k] * rc * W1[k * 64 + j];
        h1g[o] = s > 0.f ? s : (expf(s) - 1.f);
    }
}

__global__ __launch_bounds__(256) void k_dom2(
    const float* __restrict__ h1g,
    const float* __restrict__ W2, const float* __restrict__ b2,
    float* __restrict__ out)
{
    int o = blockIdx.x * 256 + threadIdx.x;       // 64*50 outputs
    if (o < 64 * N_PATIENTS) {
        int i = o / N_PATIENTS, p = o - i * N_PATIENTS;
        float s = b2[p];
        #pragma unroll 8
        for (int k = 0; k < 64; k++) s += h1g[i * 64 + k] * W2[k * N_PATIENTS + p];
        out[o] = s;
    }
}

// ---------------- launch ----------------

extern "C" void kernel_launch(void* const* d_in, const int* in_sizes, int n_in,
                              void* d_out, int out_size, void* d_ws, size_t ws_size,
                              hipStream_t stream) {
    const float* x     = (const float*)d_in[0];
    const int*   ei    = (const int*)d_in[1];
    const int*   batch = (const int*)d_in[2];
    const float* Wroot = (const float*)d_in[3];
    const float* Wrel  = (const float*)d_in[4];
    const float* bconv = (const float*)d_in[5];
    const float* gamma = (const float*)d_in[6];
    const float* beta  = (const float*)d_in[7];
    const float* bW    = (const float*)d_in[8];
    const float* bb    = (const float*)d_in[9];
    const float* W1    = (const float*)d_in[10];
    const float* b1    = (const float*)d_in[11];
    const float* W2    = (const float*)d_in[12];
    const float* b2    = (const float*)d_in[13];
    float* out = (float*)d_out;

    char* ws = (char*)d_ws;
    size_t off = 0;
    auto alloc = [&](size_t bytes) -> char* {
        char* p = ws + off;
        off += (bytes + 255) & ~(size_t)255;
        return p;
    };
    unsigned short* xhiA    = (unsigned short*)alloc((size_t)N_NODES * DIM * 2);
    unsigned short* xhiB    = (unsigned short*)alloc((size_t)N_NODES * DIM * 2);
    unsigned short* xloA    = (unsigned short*)alloc((size_t)N_NODES * DIM * 2);
    unsigned short* xloB    = (unsigned short*)alloc((size_t)N_NODES * DIM * 2);
    unsigned short* Wt      = (unsigned short*)alloc((size_t)NLAYERS * DIM * 256 * 2);
    int*            counts  = (int*)alloc((size_t)N_NODES * 4);
    int*            incl    = (int*)alloc((size_t)N_NODES * 4);
    int*            row_ptr = (int*)alloc((size_t)(N_NODES + 1) * 4);
    int*            cursor  = (int*)alloc((size_t)N_NODES * 4);
    int*            esorted = (int*)alloc((size_t)N_EDGES * 4);
    int*            bsums   = (int*)alloc(256 * 4);
    float*          pooled  = (float*)alloc((size_t)N_GRAPHS * DIM * 4);
    int*            gcount  = (int*)alloc((size_t)N_GRAPHS * 4);
    float*          h1g     = (float*)alloc((size_t)64 * 64 * 4);
    (void)ws_size; (void)in_sizes; (void)n_in; (void)out_size;

    hipMemsetAsync(counts, 0, (size_t)N_NODES * 4, stream);
    hipMemsetAsync(pooled, 0, (size_t)N_GRAPHS * DIM * 4, stream);

    k_prep<<<(N_NODES * DIM / 8 + 255) / 256, 256, 0, stream>>>(x, xhiA, xloA, Wroot, Wrel, Wt);
    k_count<<<(N_EDGES + 255) / 256, 256, 0, stream>>>(ei, counts);
    int nb = (N_NODES + 255) / 256;
    k_scan_a<<<nb, 256, 0, stream>>>(counts, incl, bsums, N_NODES);
    k_scan_b<<<1, 256, 0, stream>>>(bsums, nb);
    k_scan_c<<<nb, 256, 0, stream>>>(counts, incl, bsums, row_ptr, cursor, N_NODES);
    k_fill<<<(N_EDGES + 255) / 256, 256, 0, stream>>>(ei, cursor, esorted);

    int lgrid = (N_NODES + ROWS - 1) / ROWS;
    const unsigned short* xhi_i = xhiA;
    const unsigned short* xlo_i = xloA;
    unsigned short* xhi_o = xhiB;
    unsigned short* xlo_o = xloB;
    for (int l = 0; l < NLAYERS; l++) {
        int last = (l == NLAYERS - 1);
        k_layer<<<lgrid, 512, 0, stream>>>(xhi_i, xlo_i, xhi_o, xlo_o,
                                           row_ptr, esorted, Wt + (size_t)l * DIM * 256,
                                           bconv + l * DIM, gamma + l * DIM, beta + l * DIM,
                                           bW, bb, out, last);
        const unsigned short* th = xhi_i; xhi_i = xhi_o; xhi_o = (unsigned short*)th;
        const unsigned short* tl = xlo_i; xlo_i = xlo_o; xlo_o = (unsigned short*)tl;
    }
    k_pool<<<N_GRAPHS * 16, 256, 0, stream>>>(xhi_i, xlo_i, batch, pooled, gcount);
    k_dom1<<<16, 256, 0, stream>>>(pooled, gcount, W1, b1, h1g);
    k_dom2<<<(64 * N_PATIENTS + 255) / 256, 256, 0, stream>>>(h1g, W2, b2, out + N_NODES);
}